// Round 6
// baseline (331.282 us; speedup 1.0000x reference)
//
#include <hip/hip_runtime.h>
#include <hip/hip_bf16.h>

#define NEMB  4096
#define DIM   128
#define NROWS 32768
#define MARGIN 3.5e-4f   // >= 2x(approx err ~4e-5) + 2x fp16 gmin ulp (3e-5), 2.5x slack

typedef _Float16 half8  __attribute__((ext_vector_type(8)));
typedef _Float16 half4v __attribute__((ext_vector_type(4)));
typedef float    float4v __attribute__((ext_vector_type(4)));

// ---------------- K1: fused split-to-fp16 + numpy-pairwise row sum-of-squares ----------
// x rows scale 1, W rows scale 2^16 (exact pow2). Pairwise sum replicates
// np.sum(a*a,axis=1) fp32 semantics exactly (8 strided accumulators + binary tree).
__launch_bounds__(256)
__global__ void k_prep(const float* __restrict__ x, const float* __restrict__ W,
                       _Float16* __restrict__ Xh, _Float16* __restrict__ Wh,
                       float* __restrict__ sxx, float* __restrict__ sww) {
    const int b = blockIdx.x;               // 4608 blocks, 8 rows each
    const int t = threadIdx.x;
    const bool isX = (b < NROWS / 8);
    const float* src   = isX ? x : W;
    _Float16*    dsth  = isX ? Xh : Wh;
    float*       dsts  = isX ? sxx : sww;
    const int    rbase = isX ? b * 8 : (b - NROWS / 8) * 8;
    const float  scale = isX ? 1.0f : 65536.0f;

    const size_t i4 = (size_t)rbase * 32 + t;
    const float4 v = ((const float4*)src)[i4];
    half4v hv = { (_Float16)(v.x * scale), (_Float16)(v.y * scale),
                  (_Float16)(v.z * scale), (_Float16)(v.w * scale) };
    *(half4v*)(dsth + i4 * 4) = hv;

    if (t < 64) {
        const int row = rbase + (t >> 3);
        const int j   = t & 7;
        const float* p = src + (size_t)row * DIM + j;
        float vv = p[0];
        float r = __fmul_rn(vv, vv);
        #pragma unroll
        for (int q = 1; q < 16; ++q) { vv = p[q * 8]; r = __fadd_rn(r, __fmul_rn(vv, vv)); }
        float o = __shfl_xor(r, 1, 64); r = __fadd_rn(r, o);
        o = __shfl_xor(r, 2, 64); r = __fadd_rn(r, o);
        o = __shfl_xor(r, 4, 64); r = __fadd_rn(r, o);
        if (j == 0) dsts[row] = r;
    }
}

// ---------------- K2: no-LDS MFMA approx scores, operands swapped ----------------
// D = W'*X^T: m = codes, n = xrows. C/D layout: n(col)=lane&15, m(row)=quad*4+reg.
// 16-code group-min = 3 in-reg mins + 2 shuffles. gmin[row][256] fp16.
// s~ = sww_c - acc*2^-15 (W scaled 2^16).
__launch_bounds__(256)
__global__ void k_score1(const _Float16* __restrict__ Xh, const _Float16* __restrict__ Wh,
                         const float* __restrict__ sww, _Float16* __restrict__ gmin) {
    const int tid  = threadIdx.x;
    const int wv   = tid >> 6;
    const int lane = tid & 63;
    const int l15  = lane & 15;
    const int quad = lane >> 4;
    const int r0   = blockIdx.x * 128;   // xrow block
    const int cb   = blockIdx.y * 128;   // code block

    float4v acc[2][8];
    #pragma unroll
    for (int tm = 0; tm < 2; ++tm)
        #pragma unroll
        for (int tn = 0; tn < 8; ++tn) acc[tm][tn] = (float4v){0.f, 0.f, 0.f, 0.f};

    // A = W codes (fragment row = l15), B = x rows (fragment row = l15)
    const _Float16* Ab = Wh + (size_t)(cb + wv * 32 + l15) * DIM + quad * 8;
    const _Float16* Bb = Xh + (size_t)(r0 + l15) * DIM + quad * 8;

    #pragma unroll
    for (int c = 0; c < 4; ++c) {
        const int k0 = c * 32;
        const half8 a0 = *(const half8*)(Ab + k0);
        const half8 a1 = *(const half8*)(Ab + 16 * DIM + k0);
        #pragma unroll
        for (int tn = 0; tn < 8; ++tn) {
            const half8 bfr = *(const half8*)(Bb + (size_t)tn * 16 * DIM + k0);
            acc[0][tn] = __builtin_amdgcn_mfma_f32_16x16x32_f16(a0, bfr, acc[0][tn], 0, 0, 0);
            acc[1][tn] = __builtin_amdgcn_mfma_f32_16x16x32_f16(a1, bfr, acc[1][tn], 0, 0, 0);
        }
    }

    float sw[2][4];
    #pragma unroll
    for (int tm = 0; tm < 2; ++tm)
        #pragma unroll
        for (int rg = 0; rg < 4; ++rg)
            sw[tm][rg] = sww[cb + wv * 32 + tm * 16 + quad * 4 + rg];

    #pragma unroll
    for (int tm = 0; tm < 2; ++tm) {
        #pragma unroll
        for (int tn = 0; tn < 8; ++tn) {
            const float4v a = acc[tm][tn];
            const float s0 = fmaf(a[0], -0x1p-15f, sw[tm][0]);
            const float s1 = fmaf(a[1], -0x1p-15f, sw[tm][1]);
            const float s2 = fmaf(a[2], -0x1p-15f, sw[tm][2]);
            const float s3 = fmaf(a[3], -0x1p-15f, sw[tm][3]);
            float m2 = fminf(fminf(s0, s1), fminf(s2, s3));
            m2 = fminf(m2, __shfl_xor(m2, 16, 64));
            m2 = fminf(m2, __shfl_xor(m2, 32, 64));
            if (quad == 0)
                gmin[(size_t)(r0 + tn * 16 + l15) * 256 + blockIdx.y * 8 + wv * 2 + tm]
                    = (_Float16)m2;
        }
    }
}

// ---------------- K3: fused flag + exact refine + gather + loss partial ----------------
// One wave per row. Flags from gmin (min over 256 groups + margin), then exact
// d = fl(fl(sxx+sww) - fl(2*dot)) on flagged 16-code groups, numpy fp32 semantics,
// lowest-index ties at every level.
__launch_bounds__(256)
__global__ void k_refine(const float* __restrict__ x, const float* __restrict__ W,
                         const float* __restrict__ sxx, const float* __restrict__ sww,
                         const _Float16* __restrict__ gmin,
                         float* __restrict__ out0, float* __restrict__ out1,
                         float* __restrict__ out_idx, float* __restrict__ part) {
    const int row  = blockIdx.x * 4 + (threadIdx.x >> 6);
    const int lane = threadIdx.x & 63;

    // flag phase: lane l holds groups 4l..4l+3
    const half4v g4 = *(const half4v*)&gmin[(size_t)row * 256 + lane * 4];
    const float v0 = (float)g4.x, v1 = (float)g4.y, v2 = (float)g4.z, v3 = (float)g4.w;
    float m = fminf(fminf(v0, v1), fminf(v2, v3));
    #pragma unroll
    for (int off = 1; off < 64; off <<= 1) m = fminf(m, __shfl_xor(m, off, 64));
    const float thr = m + MARGIN;
    unsigned long long bal[4];
    bal[0] = __ballot(v0 <= thr);
    bal[1] = __ballot(v1 <= thr);
    bal[2] = __ballot(v2 <= thr);
    bal[3] = __ballot(v3 <= thr);

    const int cig = lane >> 2;     // code within group
    const int kp  = lane & 3;      // k quarter
    const float sxr = sxx[row];
    const float* xr = x + (size_t)row * DIM;
    const float* xp = xr + kp * 32;

    float bv = 3.0e38f;
    int   bi = 0x7fffffff;

    #pragma unroll
    for (int j = 0; j < 4; ++j) {
        unsigned long long msk = bal[j];
        while (msk) {
            const int l = __builtin_ctzll(msk);
            msk &= msk - 1;
            const int g = l * 4 + j;
            const int c = g * 16 + cig;
            const float* wr = W + (size_t)c * DIM + kp * 32;
            float dot = 0.f;
            #pragma unroll
            for (int k = 0; k < 32; ++k) dot = fmaf(xp[k], wr[k], dot);
            float o = __shfl_xor(dot, 1, 64); dot = __fadd_rn(dot, o);
            o = __shfl_xor(dot, 2, 64); dot = __fadd_rn(dot, o);   // (p0+p1)+(p2+p3)
            const float A = __fadd_rn(sxr, sww[c]);
            const float d = __fsub_rn(A, __fmul_rn(2.0f, dot));
            if (d < bv || (d == bv && c < bi)) { bv = d; bi = c; }
        }
    }
    #pragma unroll
    for (int off = 1; off < 64; off <<= 1) {
        const float ov = __shfl_xor(bv, off, 64);
        const int   oi = __shfl_xor(bi, off, 64);
        if (ov < bv || (ov == bv && oi < bi)) { bv = ov; bi = oi; }
    }

    const float2 wv2 = *(const float2*)(W + (size_t)bi * DIM + lane * 2);
    const float2 xv2 = *(const float2*)(xr + lane * 2);
    const float d0 = wv2.x - xv2.x, d1 = wv2.y - xv2.y;
    float p = fmaf(d0, d0, d1 * d1);
    *(float2*)(out0 + (size_t)row * DIM + lane * 2) = wv2;
    *(float2*)(out1 + (size_t)row * DIM + lane * 2) = wv2;
    #pragma unroll
    for (int off = 32; off > 0; off >>= 1) p += __shfl_down(p, off, 64);
    if (lane == 0) {
        part[row] = p;
        out_idx[row] = (float)bi;
    }
}

// ---------------- K4: reduce 32768 partials -> loss (1024 threads, 8-way ILP) --------
__global__ void k_lsum(const float* __restrict__ part, float* __restrict__ out_loss) {
    __shared__ float red[1024];
    const int tid = threadIdx.x;
    const float4* p4 = (const float4*)part;   // 8192 float4
    float s = 0.f;
    #pragma unroll
    for (int i = 0; i < 8; ++i) {
        const float4 v = p4[tid + i * 1024];
        s += (v.x + v.y) + (v.z + v.w);
    }
    red[tid] = s;
    __syncthreads();
    #pragma unroll
    for (int w = 512; w > 0; w >>= 1) {
        if (tid < w) red[tid] += red[tid + w];
        __syncthreads();
    }
    if (tid == 0) out_loss[0] = red[0] * 1.25f / (float)(NROWS * DIM);
}

extern "C" void kernel_launch(void* const* d_in, const int* in_sizes, int n_in,
                              void* d_out, int out_size, void* d_ws, size_t ws_size,
                              hipStream_t stream) {
    const float* x = (const float*)d_in[0];   // [32768,128]
    const float* W = (const float*)d_in[1];   // [4096,128]
    float* out = (float*)d_out;

    float* out_q2d  = out;
    float* out_qst  = out + (size_t)NROWS * DIM;
    float* out_loss = out + (size_t)2 * NROWS * DIM;
    float* out_idx  = out + (size_t)2 * NROWS * DIM + 1;

    // ws layout (float slots), ~26.5 MB total
    float* ws   = (float*)d_ws;
    float* sww  = ws;                                   // 4096
    float* sxx  = ws + 4096;                            // 32768
    float* part = ws + 4096 + 32768;                    // 32768
    _Float16* gmin = (_Float16*)(ws + 4096 + 2 * 32768);   // 32768*256 fp16 = 16.8 MB
    _Float16* Xh = gmin + (size_t)NROWS * 256;          // 32768*128 fp16
    _Float16* Wh = Xh + (size_t)NROWS * DIM;            // 4096*128 fp16

    k_prep<<<(NROWS + NEMB) / 8, 256, 0, stream>>>(x, W, Xh, Wh, sxx, sww);
    dim3 g2(NROWS / 128, NEMB / 128);
    k_score1<<<g2, 256, 0, stream>>>(Xh, Wh, sww, gmin);
    k_refine<<<NROWS / 4, 256, 0, stream>>>(x, W, sxx, sww, gmin,
                                            out_q2d, out_qst, out_idx, part);
    k_lsum<<<1, 1024, 0, stream>>>(part, out_loss);
}

// Round 7
// 229.139 us; speedup vs baseline: 1.4458x; 1.4458x over previous
//
#include <hip/hip_runtime.h>
#include <hip/hip_bf16.h>

#define NEMB  4096
#define DIM   128
#define NROWS 32768
#define MARGIN 3.5e-4f   // >= 2x(approx err ~3.5e-5), 5x slack; validated r5/r6
#define RPB   64         // rows per block -> grid 512 = 2 blocks/CU

typedef _Float16 half8  __attribute__((ext_vector_type(8)));
typedef _Float16 half4v __attribute__((ext_vector_type(4)));
typedef _Float16 half2v __attribute__((ext_vector_type(2)));
typedef float    float4v __attribute__((ext_vector_type(4)));

typedef const __attribute__((address_space(1))) void* gas_ptr;
typedef __attribute__((address_space(3))) void*       las_ptr;

__device__ __forceinline__ void gload16(const void* g, void* l) {
    __builtin_amdgcn_global_load_lds((gas_ptr)g, (las_ptr)l, 16, 0, 0);
}

__device__ __forceinline__ half2v hmin2(half2v a, half2v b) {
    half2v r;
    r.x = (a.x < b.x) ? a.x : b.x;
    r.y = (a.y < b.y) ? a.y : b.y;
    return r;
}

// ---------------- K1: split-to-fp16 + numpy-pairwise row sum-of-squares ----------------
// x rows scale 1, W rows scale 2^16 (exact pow2). Pairwise sum replicates
// np.sum(a*a,axis=1) fp32 semantics exactly. (validated r3-r6)
__launch_bounds__(256)
__global__ void k_prep(const float* __restrict__ x, const float* __restrict__ W,
                       _Float16* __restrict__ Xh, _Float16* __restrict__ Wh,
                       float* __restrict__ sxx, float* __restrict__ sww) {
    const int b = blockIdx.x;               // 4608 blocks, 8 rows each
    const int t = threadIdx.x;
    const bool isX = (b < NROWS / 8);
    const float* src   = isX ? x : W;
    _Float16*    dsth  = isX ? Xh : Wh;
    float*       dsts  = isX ? sxx : sww;
    const int    rbase = isX ? b * 8 : (b - NROWS / 8) * 8;
    const float  scale = isX ? 1.0f : 65536.0f;

    const size_t i4 = (size_t)rbase * 32 + t;
    const float4 v = ((const float4*)src)[i4];
    half4v hv = { (_Float16)(v.x * scale), (_Float16)(v.y * scale),
                  (_Float16)(v.z * scale), (_Float16)(v.w * scale) };
    *(half4v*)(dsth + i4 * 4) = hv;

    if (t < 64) {
        const int row = rbase + (t >> 3);
        const int j   = t & 7;
        const float* p = src + (size_t)row * DIM + j;
        float vv = p[0];
        float r = __fmul_rn(vv, vv);
        #pragma unroll
        for (int q = 1; q < 16; ++q) { vv = p[q * 8]; r = __fadd_rn(r, __fmul_rn(vv, vv)); }
        float o = __shfl_xor(r, 1, 64); r = __fadd_rn(r, o);
        o = __shfl_xor(r, 2, 64); r = __fadd_rn(r, o);
        o = __shfl_xor(r, 4, 64); r = __fadd_rn(r, o);
        if (j == 0) dsts[row] = r;
    }
}

// ---------------- K2: mega kernel — score all 4096 codes for 64 rows, flag, refine ------
// sA: W code-block (128x128 fp16, 32 KB), k-unit-swizzled so DMA's lane-contiguous
//     constraint coexists with conflict-free b128 frag reads:
//     16B-unit (code m, kq) stored at byte m*256 + ((kq+m)&15)*16.
// gbuf: per-row 256 group-minima fp16, slot-swizzled: (row, g) at slot (g+2*row)&255,
//     byte row*512 + slot*2  -> conflict-free packed-half2 writes.
__launch_bounds__(256, 2)
__global__ void k_main(const _Float16* __restrict__ Xh, const _Float16* __restrict__ Wh,
                       const float* __restrict__ x, const float* __restrict__ W,
                       const float* __restrict__ sxx, const float* __restrict__ sww,
                       float* __restrict__ out0, float* __restrict__ out1,
                       float* __restrict__ out_idx, float* __restrict__ part) {
    __shared__ _Float16 sA[128 * 128];      // 32 KB
    __shared__ _Float16 gbuf[RPB * 256];    // 32 KB

    const int tid  = threadIdx.x;
    const int wv   = tid >> 6;
    const int lane = tid & 63;
    const int l15  = lane & 15;
    const int quad = lane >> 4;
    const int r0   = blockIdx.x * RPB;

    // B fragments (X rows r0..r0+63) live in registers for the whole kernel
    half8 bfr[4][4];
    #pragma unroll
    for (int tn = 0; tn < 4; ++tn)
        #pragma unroll
        for (int c = 0; c < 4; ++c)
            bfr[tn][c] = *(const half8*)(Xh + (size_t)(r0 + tn * 16 + l15) * DIM + c * 32 + quad * 8);

    const int c_loc  = lane >> 4;   // code-within-DMA-chunk
    const int u_slot = lane & 15;   // 16B unit slot

    // issue DMA for cb = 0
    #pragma unroll
    for (int i = 0; i < 8; ++i) {
        const int code_base = (wv * 8 + i) * 4;
        const int cib = code_base + c_loc;
        const int kq  = (u_slot - cib) & 15;
        gload16(Wh + ((size_t)cib << 7) + kq * 8, (char*)sA + code_base * 256);
    }

    for (int cb = 0; cb < 32; ++cb) {
        float4v acc[2][4];
        #pragma unroll
        for (int tm = 0; tm < 2; ++tm)
            #pragma unroll
            for (int tn = 0; tn < 4; ++tn) acc[tm][tn] = (float4v){0.f, 0.f, 0.f, 0.f};

        __syncthreads();   // DMA for cb landed (barrier drains vmcnt)

        #pragma unroll
        for (int c = 0; c < 4; ++c) {
            const int m0 = wv * 32 + l15;
            const int m1 = m0 + 16;
            const int kq = c * 4 + quad;
            const half8 a0 = *(const half8*)((const char*)sA + m0 * 256 + (((kq + m0) & 15) << 4));
            const half8 a1 = *(const half8*)((const char*)sA + m1 * 256 + (((kq + m1) & 15) << 4));
            #pragma unroll
            for (int tn = 0; tn < 4; ++tn) {
                acc[0][tn] = __builtin_amdgcn_mfma_f32_16x16x32_f16(a0, bfr[tn][c], acc[0][tn], 0, 0, 0);
                acc[1][tn] = __builtin_amdgcn_mfma_f32_16x16x32_f16(a1, bfr[tn][c], acc[1][tn], 0, 0, 0);
            }
        }
        __syncthreads();   // all waves done reading sA

        if (cb + 1 < 32) { // prefetch next W code-block (overlaps epilogue)
            #pragma unroll
            for (int i = 0; i < 8; ++i) {
                const int code_base = (wv * 8 + i) * 4;
                const int cib = code_base + c_loc;
                const int kq  = (u_slot - cib) & 15;
                gload16(Wh + ((size_t)((cb + 1) * 128 + cib) << 7) + kq * 8,
                        (char*)sA + code_base * 256);
            }
        }

        // epilogue: s~ = sww - acc*2^-15, 16-code-group minima -> gbuf (2 shfl per tn)
        const float4 sw0 = ((const float4*)sww)[cb * 32 + wv * 8 + 0 + quad];
        const float4 sw1 = ((const float4*)sww)[cb * 32 + wv * 8 + 4 + quad];
        #pragma unroll
        for (int tn = 0; tn < 4; ++tn) {
            float s0 = fmaf(acc[0][tn][0], -0x1p-15f, sw0.x);
            s0 = fminf(s0, fmaf(acc[0][tn][1], -0x1p-15f, sw0.y));
            s0 = fminf(s0, fmaf(acc[0][tn][2], -0x1p-15f, sw0.z));
            s0 = fminf(s0, fmaf(acc[0][tn][3], -0x1p-15f, sw0.w));
            float s1 = fmaf(acc[1][tn][0], -0x1p-15f, sw1.x);
            s1 = fminf(s1, fmaf(acc[1][tn][1], -0x1p-15f, sw1.y));
            s1 = fminf(s1, fmaf(acc[1][tn][2], -0x1p-15f, sw1.z));
            s1 = fminf(s1, fmaf(acc[1][tn][3], -0x1p-15f, sw1.w));
            union { half2v h; int u; } cur, oth;
            cur.h.x = (_Float16)s0; cur.h.y = (_Float16)s1;   // groups cb*8+wv*2, +1
            oth.u = __shfl_xor(cur.u, 16, 64); cur.h = hmin2(cur.h, oth.h);
            oth.u = __shfl_xor(cur.u, 32, 64); cur.h = hmin2(cur.h, oth.h);
            if (quad == 0) {
                const int row  = tn * 16 + l15;
                const int slot = (cb * 8 + wv * 2 + 2 * row) & 255;
                *(half2v*)((char*)gbuf + row * 512 + slot * 2) = cur.h;
            }
        }
    }

    __syncthreads();

    // ---- flag + exact refine (numpy fp32 semantics) + outputs ----
    const int chunk = lane & 31;   // groups 8*chunk .. 8*chunk+7
    const int cig   = lane >> 2;
    const int kp    = lane & 3;
    for (int t = 0; t < 16; ++t) {
        const int lr  = wv * 16 + t;
        const int row = r0 + lr;

        float v[8];
        #pragma unroll
        for (int k = 0; k < 4; ++k) {
            const int slot = (8 * chunk + 2 * k + 2 * lr) & 255;
            const half2v h = *(const half2v*)((const char*)gbuf + lr * 512 + slot * 2);
            v[2 * k]     = (float)h.x;
            v[2 * k + 1] = (float)h.y;
        }
        float m = v[0];
        #pragma unroll
        for (int k = 1; k < 8; ++k) m = fminf(m, v[k]);
        #pragma unroll
        for (int off = 1; off < 32; off <<= 1) m = fminf(m, __shfl_xor(m, off, 64));
        const float thr = m + MARGIN;

        unsigned bal[8];
        #pragma unroll
        for (int j = 0; j < 8; ++j) bal[j] = (unsigned)__ballot(v[j] <= thr);

        const float sxr = sxx[row];
        const float* xr = x + (size_t)row * DIM;
        const float* xp = xr + kp * 32;
        float bv = 3.0e38f;
        int   bi = 0x7fffffff;

        #pragma unroll
        for (int j = 0; j < 8; ++j) {
            unsigned msk = bal[j];
            while (msk) {
                const int l = __builtin_ctz(msk);
                msk &= msk - 1;
                const int g = l * 8 + j;
                const int c = g * 16 + cig;
                const float* wr = W + (size_t)c * DIM + kp * 32;
                float dot = 0.f;
                #pragma unroll
                for (int k = 0; k < 32; ++k) dot = fmaf(xp[k], wr[k], dot);
                float o = __shfl_xor(dot, 1, 64); dot = __fadd_rn(dot, o);
                o = __shfl_xor(dot, 2, 64); dot = __fadd_rn(dot, o);  // (p0+p1)+(p2+p3)
                const float A = __fadd_rn(sxr, sww[c]);
                const float d = __fsub_rn(A, __fmul_rn(2.0f, dot));
                if (d < bv || (d == bv && c < bi)) { bv = d; bi = c; }
            }
        }
        #pragma unroll
        for (int off = 1; off < 64; off <<= 1) {
            const float ov = __shfl_xor(bv, off, 64);
            const int   oi = __shfl_xor(bi, off, 64);
            if (ov < bv || (ov == bv && oi < bi)) { bv = ov; bi = oi; }
        }

        const float2 wv2 = *(const float2*)(W + (size_t)bi * DIM + lane * 2);
        const float2 xv2 = *(const float2*)(xr + lane * 2);
        const float d0 = wv2.x - xv2.x, d1 = wv2.y - xv2.y;
        float p = fmaf(d0, d0, d1 * d1);
        *(float2*)(out0 + (size_t)row * DIM + lane * 2) = wv2;
        *(float2*)(out1 + (size_t)row * DIM + lane * 2) = wv2;
        #pragma unroll
        for (int off = 32; off > 0; off >>= 1) p += __shfl_down(p, off, 64);
        if (lane == 0) {
            part[row] = p;
            out_idx[row] = (float)bi;
        }
    }
}

// ---------------- K3: reduce 32768 partials -> loss ----------------
__global__ void k_lsum(const float* __restrict__ part, float* __restrict__ out_loss) {
    __shared__ float red[1024];
    const int tid = threadIdx.x;
    const float4* p4 = (const float4*)part;   // 8192 float4
    float s = 0.f;
    #pragma unroll
    for (int i = 0; i < 8; ++i) {
        const float4 v = p4[tid + i * 1024];
        s += (v.x + v.y) + (v.z + v.w);
    }
    red[tid] = s;
    __syncthreads();
    #pragma unroll
    for (int w = 512; w > 0; w >>= 1) {
        if (tid < w) red[tid] += red[tid + w];
        __syncthreads();
    }
    if (tid == 0) out_loss[0] = red[0] * 1.25f / (float)(NROWS * DIM);
}

extern "C" void kernel_launch(void* const* d_in, const int* in_sizes, int n_in,
                              void* d_out, int out_size, void* d_ws, size_t ws_size,
                              hipStream_t stream) {
    const float* x = (const float*)d_in[0];   // [32768,128]
    const float* W = (const float*)d_in[1];   // [4096,128]
    float* out = (float*)d_out;

    float* out_q2d  = out;
    float* out_qst  = out + (size_t)NROWS * DIM;
    float* out_loss = out + (size_t)2 * NROWS * DIM;
    float* out_idx  = out + (size_t)2 * NROWS * DIM + 1;

    // ws layout (float slots), ~9 MB total
    float* ws   = (float*)d_ws;
    float* sww  = ws;                                   // 4096
    float* sxx  = ws + 4096;                            // 32768
    float* part = ws + 4096 + 32768;                    // 32768
    _Float16* Xh = (_Float16*)(ws + 4096 + 2 * 32768);  // 32768*128 fp16
    _Float16* Wh = Xh + (size_t)NROWS * DIM;            // 4096*128 fp16

    k_prep<<<(NROWS + NEMB) / 8, 256, 0, stream>>>(x, W, Xh, Wh, sxx, sww);
    k_main<<<NROWS / RPB, 256, 0, stream>>>(Xh, Wh, x, W, sxx, sww,
                                            out_q2d, out_qst, out_idx, part);
    k_lsum<<<1, 1024, 0, stream>>>(part, out_loss);
}